// Round 3
// baseline (1140.133 us; speedup 1.0000x reference)
//
#include <hip/hip_runtime.h>
#include <math.h>

#define N_NODES 100000
#define N_EDGES 3200000
#define BSHIFT 7
#define BNODES 128                         // nodes per bucket
#define NB 782                             // ceil(N_NODES/128)
#define ACC_STRIDE 17                      // padded node stride in LDS acc

// ---------------------------------------------------------------------------
// gemm1: h[N,16] = x[N,512] @ W1[512,16]   (unchanged)
// ---------------------------------------------------------------------------
__global__ __launch_bounds__(256) void gemm1_kernel(
    const float* __restrict__ x, const float* __restrict__ W1,
    float* __restrict__ h, int nrows)
{
    __shared__ float xs[32 * 260];
    const int t = threadIdx.x;
    const int rbase = blockIdx.x * 256;
    const int rq = t >> 2;
    const int cg = t & 3;

    float4 acc0 = make_float4(0.f, 0.f, 0.f, 0.f);
    float4 acc1 = acc0, acc2 = acc0, acc3 = acc0;

    const int kl4  = (t & 7) * 4;
    const int rstg = t >> 3;
    const float4* w4 = (const float4*)W1;

    for (int kc = 0; kc < 512; kc += 32) {
        #pragma unroll
        for (int i = 0; i < 8; ++i) {
            int row = rstg + i * 32;
            int rg  = rbase + row;
            float4 v = make_float4(0.f, 0.f, 0.f, 0.f);
            if (rg < nrows)
                v = *(const float4*)(x + (size_t)rg * 512 + kc + kl4);
            xs[(kl4 + 0) * 260 + row] = v.x;
            xs[(kl4 + 1) * 260 + row] = v.y;
            xs[(kl4 + 2) * 260 + row] = v.z;
            xs[(kl4 + 3) * 260 + row] = v.w;
        }
        __syncthreads();

        #pragma unroll
        for (int k4 = 0; k4 < 8; ++k4) {
            const int k0 = k4 * 4;
            float4 xv0 = *(const float4*)(xs + (k0 + 0) * 260 + rq * 4);
            float4 xv1 = *(const float4*)(xs + (k0 + 1) * 260 + rq * 4);
            float4 xv2 = *(const float4*)(xs + (k0 + 2) * 260 + rq * 4);
            float4 xv3 = *(const float4*)(xs + (k0 + 3) * 260 + rq * 4);
            float4 wv0 = w4[(kc + k0 + 0) * 4 + cg];
            float4 wv1 = w4[(kc + k0 + 1) * 4 + cg];
            float4 wv2 = w4[(kc + k0 + 2) * 4 + cg];
            float4 wv3 = w4[(kc + k0 + 3) * 4 + cg];

            #define GCN_UPD(xv, wv)                                           \
                acc0.x += (xv).x * (wv).x; acc0.y += (xv).x * (wv).y;         \
                acc0.z += (xv).x * (wv).z; acc0.w += (xv).x * (wv).w;         \
                acc1.x += (xv).y * (wv).x; acc1.y += (xv).y * (wv).y;         \
                acc1.z += (xv).y * (wv).z; acc1.w += (xv).y * (wv).w;         \
                acc2.x += (xv).z * (wv).x; acc2.y += (xv).z * (wv).y;         \
                acc2.z += (xv).z * (wv).z; acc2.w += (xv).z * (wv).w;         \
                acc3.x += (xv).w * (wv).x; acc3.y += (xv).w * (wv).y;         \
                acc3.z += (xv).w * (wv).z; acc3.w += (xv).w * (wv).w;
            GCN_UPD(xv0, wv0)
            GCN_UPD(xv1, wv1)
            GCN_UPD(xv2, wv2)
            GCN_UPD(xv3, wv3)
            #undef GCN_UPD
        }
        __syncthreads();
    }
    {
        int rg = rbase + rq * 4;
        if (rg + 0 < nrows) *(float4*)(h + (size_t)(rg + 0) * 16 + cg * 4) = acc0;
        if (rg + 1 < nrows) *(float4*)(h + (size_t)(rg + 1) * 16 + cg * 4) = acc1;
        if (rg + 2 < nrows) *(float4*)(h + (size_t)(rg + 2) * 16 + cg * 4) = acc2;
        if (rg + 3 < nrows) *(float4*)(h + (size_t)(rg + 3) * 16 + cg * 4) = acc3;
    }
}

// ---------------------------------------------------------------------------
// Binning: bucket = dst >> 7.  Edge payload packed: src | (dst&127)<<17.
// ---------------------------------------------------------------------------
__global__ __launch_bounds__(256) void bin_count_kernel(
    const int* __restrict__ ei, int* __restrict__ bucket_cnt)
{
    __shared__ int hist[NB];
    const int t = threadIdx.x;
    for (int i = t; i < NB; i += 256) hist[i] = 0;
    __syncthreads();
    const int stride = gridDim.x * 256;
    for (int e = blockIdx.x * 256 + t; e < N_EDGES; e += stride)
        atomicAdd(&hist[ei[N_EDGES + e] >> BSHIFT], 1);
    __syncthreads();
    for (int i = t; i < NB; i += 256)
        if (hist[i]) atomicAdd(&bucket_cnt[i], hist[i]);
}

__global__ __launch_bounds__(1024) void bucket_scan_kernel(
    const int* __restrict__ bucket_cnt, int* __restrict__ bucket_base,
    int* __restrict__ bucket_cursor)
{
    __shared__ int s[1024];
    const int t = threadIdx.x;
    s[t] = (t < NB) ? bucket_cnt[t] : 0;
    __syncthreads();
    for (int off = 1; off < 1024; off <<= 1) {
        int v = (t >= off) ? s[t - off] : 0;
        __syncthreads();
        s[t] += v;
        __syncthreads();
    }
    if (t < NB) {
        int excl = (t == 0) ? 0 : s[t - 1];
        bucket_base[t]   = excl;
        bucket_cursor[t] = excl;
        if (t == NB - 1) bucket_base[NB] = s[t];
    }
}

#define PLACE_BLOCKS 400
__global__ __launch_bounds__(256) void bin_place_kernel(
    const int* __restrict__ ei, int* __restrict__ bucket_cursor,
    int* __restrict__ packed)
{
    __shared__ int cnt[NB];
    __shared__ int base_off[NB];
    __shared__ int cur[NB];
    const int t = threadIdx.x;
    const int chunk = (N_EDGES + PLACE_BLOCKS - 1) / PLACE_BLOCKS;   // 8000
    const int cs = blockIdx.x * chunk;
    const int ce = min(cs + chunk, N_EDGES);

    for (int i = t; i < NB; i += 256) { cnt[i] = 0; cur[i] = 0; }
    __syncthreads();
    for (int e = cs + t; e < ce; e += 256)
        atomicAdd(&cnt[ei[N_EDGES + e] >> BSHIFT], 1);
    __syncthreads();
    for (int i = t; i < NB; i += 256)
        base_off[i] = cnt[i] ? atomicAdd(&bucket_cursor[i], cnt[i]) : 0;
    __syncthreads();
    for (int e = cs + t; e < ce; e += 256) {
        int s = ei[e];
        int d = ei[N_EDGES + e];
        int b = d >> BSHIFT;
        int pos = base_off[b] + atomicAdd(&cur[b], 1);
        packed[pos] = s | ((d & (BNODES - 1)) << 17);
    }
}

// ---------------------------------------------------------------------------
// scatter_bucket1: block = one bucket (128 dst nodes). LDS accumulator,
// ds_add_f32, coalesced flush with fused +b1 / relu.
// Wave layout: 16 lanes per edge (one 64B feature line), 2 edges unrolled.
// ---------------------------------------------------------------------------
__global__ __launch_bounds__(512) void scatter_bucket1_kernel(
    const int* __restrict__ bucket_base, const int* __restrict__ packed,
    const float* __restrict__ h, const float* __restrict__ b1,
    float* __restrict__ h1)
{
    __shared__ float acc[BNODES * ACC_STRIDE];
    const int t = threadIdx.x;
    const int b = blockIdx.x;
    for (int i = t; i < BNODES * ACC_STRIDE; i += 512) acc[i] = 0.f;
    __syncthreads();

    const int bstart = bucket_base[b];
    const int bend   = bucket_base[b + 1];
    const int qid = t >> 4;        // 0..31 edge slots
    const int c   = t & 15;

    int e = bstart + qid;
    for (; e + 32 < bend; e += 64) {
        int p0 = packed[e];
        int p1 = packed[e + 32];
        float v0 = h[(p0 & 0x1FFFF) * 16 + c];
        float v1 = h[(p1 & 0x1FFFF) * 16 + c];
        atomicAdd(&acc[(p0 >> 17) * ACC_STRIDE + c], v0);
        atomicAdd(&acc[(p1 >> 17) * ACC_STRIDE + c], v1);
    }
    if (e < bend) {
        int p0 = packed[e];
        float v0 = h[(p0 & 0x1FFFF) * 16 + c];
        atomicAdd(&acc[(p0 >> 17) * ACC_STRIDE + c], v0);
    }
    __syncthreads();

    // flush: 512 threads x one float4 = 128 nodes x 16 ch
    {
        int node = t >> 2;
        int cq   = (t & 3) * 4;
        int g    = b * BNODES + node;
        if (g < N_NODES) {
            float4 v;
            v.x = fmaxf(acc[node * ACC_STRIDE + cq + 0] + b1[cq + 0], 0.f);
            v.y = fmaxf(acc[node * ACC_STRIDE + cq + 1] + b1[cq + 1], 0.f);
            v.z = fmaxf(acc[node * ACC_STRIDE + cq + 2] + b1[cq + 2], 0.f);
            v.w = fmaxf(acc[node * ACC_STRIDE + cq + 3] + b1[cq + 3], 0.f);
            *(float4*)(h1 + (size_t)g * 16 + cq) = v;
        }
    }
}

// ---------------------------------------------------------------------------
// scatter_bucket2: same accumulation over h1, epilogue = gemm2 + bias +
// log_softmax fused (one thread per node, LDS stride-17 reads conflict-free).
// ---------------------------------------------------------------------------
__global__ __launch_bounds__(512) void scatter_bucket2_kernel(
    const int* __restrict__ bucket_base, const int* __restrict__ packed,
    const float* __restrict__ h1, const float* __restrict__ W2,
    const float* __restrict__ b2, float* __restrict__ out)
{
    __shared__ float acc[BNODES * ACC_STRIDE];
    __shared__ float4 w2s[160];     // 16x40
    __shared__ float4 b2s[10];
    const int t = threadIdx.x;
    const int b = blockIdx.x;
    for (int i = t; i < BNODES * ACC_STRIDE; i += 512) acc[i] = 0.f;
    if (t < 160) w2s[t] = ((const float4*)W2)[t];
    else if (t < 170) b2s[t - 160] = ((const float4*)b2)[t - 160];
    __syncthreads();

    const int bstart = bucket_base[b];
    const int bend   = bucket_base[b + 1];
    const int qid = t >> 4;
    const int c   = t & 15;

    int e = bstart + qid;
    for (; e + 32 < bend; e += 64) {
        int p0 = packed[e];
        int p1 = packed[e + 32];
        float v0 = h1[(p0 & 0x1FFFF) * 16 + c];
        float v1 = h1[(p1 & 0x1FFFF) * 16 + c];
        atomicAdd(&acc[(p0 >> 17) * ACC_STRIDE + c], v0);
        atomicAdd(&acc[(p1 >> 17) * ACC_STRIDE + c], v1);
    }
    if (e < bend) {
        int p0 = packed[e];
        float v0 = h1[(p0 & 0x1FFFF) * 16 + c];
        atomicAdd(&acc[(p0 >> 17) * ACC_STRIDE + c], v0);
    }
    __syncthreads();

    // epilogue: threads 0..127 each finish one node
    if (t < BNODES) {
        int g = b * BNODES + t;
        if (g < N_NODES) {
            float a[16];
            #pragma unroll
            for (int k = 0; k < 16; ++k) a[k] = acc[t * ACC_STRIDE + k];

            float4 z[10];
            #pragma unroll
            for (int c4 = 0; c4 < 10; ++c4) z[c4] = b2s[c4];
            #pragma unroll
            for (int k = 0; k < 16; ++k) {
                const float av = a[k];
                #pragma unroll
                for (int c4 = 0; c4 < 10; ++c4) {
                    float4 w = w2s[k * 10 + c4];
                    z[c4].x += av * w.x;
                    z[c4].y += av * w.y;
                    z[c4].z += av * w.z;
                    z[c4].w += av * w.w;
                }
            }
            float m = z[0].x;
            #pragma unroll
            for (int c4 = 0; c4 < 10; ++c4) {
                m = fmaxf(m, z[c4].x); m = fmaxf(m, z[c4].y);
                m = fmaxf(m, z[c4].z); m = fmaxf(m, z[c4].w);
            }
            float s = 0.f;
            #pragma unroll
            for (int c4 = 0; c4 < 10; ++c4) {
                s += __expf(z[c4].x - m); s += __expf(z[c4].y - m);
                s += __expf(z[c4].z - m); s += __expf(z[c4].w - m);
            }
            const float lse = m + __logf(s);
            float4* op = (float4*)(out + (size_t)g * 40);
            #pragma unroll
            for (int c4 = 0; c4 < 10; ++c4) {
                float4 o;
                o.x = z[c4].x - lse; o.y = z[c4].y - lse;
                o.z = z[c4].z - lse; o.w = z[c4].w - lse;
                op[c4] = o;
            }
        }
    }
}

// ---------------------------------------------------------------------------
extern "C" void kernel_launch(void* const* d_in, const int* in_sizes, int n_in,
                              void* d_out, int out_size, void* d_ws, size_t ws_size,
                              hipStream_t stream)
{
    const float* x  = (const float*)d_in[0];
    const int*   ei = (const int*)d_in[1];
    const float* W1 = (const float*)d_in[2];
    const float* b1 = (const float*)d_in[3];
    const float* W2 = (const float*)d_in[4];
    const float* b2 = (const float*)d_in[5];
    float* out = (float*)d_out;

    // ws layout: h (N*16 f32), h1 (N*16 f32), packed (E int),
    //            bucket_cnt (NB), bucket_base (NB+1), bucket_cursor (NB)
    float* h    = (float*)d_ws;
    float* h1   = h + (size_t)N_NODES * 16;
    int*   packed = (int*)(h1 + (size_t)N_NODES * 16);
    int*   bcnt = packed + N_EDGES;
    int*   bbase = bcnt + NB;
    int*   bcur = bbase + (NB + 1);

    const int node_blocks = (N_NODES + 255) / 256;   // 391

    hipMemsetAsync(bcnt, 0, NB * sizeof(int), stream);
    bin_count_kernel  <<<256, 256, 0, stream>>>(ei, bcnt);
    bucket_scan_kernel<<<1, 1024, 0, stream>>>(bcnt, bbase, bcur);
    bin_place_kernel  <<<PLACE_BLOCKS, 256, 0, stream>>>(ei, bcur, packed);

    gemm1_kernel<<<node_blocks, 256, 0, stream>>>(x, W1, h, N_NODES);

    scatter_bucket1_kernel<<<NB, 512, 0, stream>>>(bbase, packed, h, b1, h1);
    scatter_bucket2_kernel<<<NB, 512, 0, stream>>>(bbase, packed, h1, W2, b2, out);
}

// Round 4
// 1138.955 us; speedup vs baseline: 1.0010x; 1.0010x over previous
//
#include <hip/hip_runtime.h>
#include <math.h>

#define N_NODES 100000
#define N_EDGES 3200000
#define BSHIFT 7
#define BNODES 128                         // nodes per bucket
#define NB 782                             // ceil(N_NODES/128)
#define ACC_STRIDE 17                      // padded node stride in LDS acc
#define PLACE_BLOCKS 400

// ---------------------------------------------------------------------------
// gemm1: h[N,16] = x[N,512] @ W1[512,16], output in sliced layout
// h_s0[node*8 + c] = channels 0..7, h_s1[node*8 + c] = channels 8..15
// ---------------------------------------------------------------------------
__global__ __launch_bounds__(256) void gemm1_kernel(
    const float* __restrict__ x, const float* __restrict__ W1,
    float* __restrict__ h_s0, float* __restrict__ h_s1, int nrows)
{
    __shared__ float xs[32 * 260];
    const int t = threadIdx.x;
    const int rbase = blockIdx.x * 256;
    const int rq = t >> 2;
    const int cg = t & 3;

    float4 acc0 = make_float4(0.f, 0.f, 0.f, 0.f);
    float4 acc1 = acc0, acc2 = acc0, acc3 = acc0;

    const int kl4  = (t & 7) * 4;
    const int rstg = t >> 3;
    const float4* w4 = (const float4*)W1;

    for (int kc = 0; kc < 512; kc += 32) {
        #pragma unroll
        for (int i = 0; i < 8; ++i) {
            int row = rstg + i * 32;
            int rg  = rbase + row;
            float4 v = make_float4(0.f, 0.f, 0.f, 0.f);
            if (rg < nrows)
                v = *(const float4*)(x + (size_t)rg * 512 + kc + kl4);
            xs[(kl4 + 0) * 260 + row] = v.x;
            xs[(kl4 + 1) * 260 + row] = v.y;
            xs[(kl4 + 2) * 260 + row] = v.z;
            xs[(kl4 + 3) * 260 + row] = v.w;
        }
        __syncthreads();

        #pragma unroll
        for (int k4 = 0; k4 < 8; ++k4) {
            const int k0 = k4 * 4;
            float4 xv0 = *(const float4*)(xs + (k0 + 0) * 260 + rq * 4);
            float4 xv1 = *(const float4*)(xs + (k0 + 1) * 260 + rq * 4);
            float4 xv2 = *(const float4*)(xs + (k0 + 2) * 260 + rq * 4);
            float4 xv3 = *(const float4*)(xs + (k0 + 3) * 260 + rq * 4);
            float4 wv0 = w4[(kc + k0 + 0) * 4 + cg];
            float4 wv1 = w4[(kc + k0 + 1) * 4 + cg];
            float4 wv2 = w4[(kc + k0 + 2) * 4 + cg];
            float4 wv3 = w4[(kc + k0 + 3) * 4 + cg];

            #define GCN_UPD(xv, wv)                                           \
                acc0.x += (xv).x * (wv).x; acc0.y += (xv).x * (wv).y;         \
                acc0.z += (xv).x * (wv).z; acc0.w += (xv).x * (wv).w;         \
                acc1.x += (xv).y * (wv).x; acc1.y += (xv).y * (wv).y;         \
                acc1.z += (xv).y * (wv).z; acc1.w += (xv).y * (wv).w;         \
                acc2.x += (xv).z * (wv).x; acc2.y += (xv).z * (wv).y;         \
                acc2.z += (xv).z * (wv).z; acc2.w += (xv).z * (wv).w;         \
                acc3.x += (xv).w * (wv).x; acc3.y += (xv).w * (wv).y;         \
                acc3.z += (xv).w * (wv).z; acc3.w += (xv).w * (wv).w;
            GCN_UPD(xv0, wv0)
            GCN_UPD(xv1, wv1)
            GCN_UPD(xv2, wv2)
            GCN_UPD(xv3, wv3)
            #undef GCN_UPD
        }
        __syncthreads();
    }
    {
        // cg 0,1 -> slice 0 (ch 0..7); cg 2,3 -> slice 1 (ch 8..15)
        float* base = (cg < 2) ? h_s0 : h_s1;
        const int off = (cg & 1) * 4;
        int rg = rbase + rq * 4;
        if (rg + 0 < nrows) *(float4*)(base + (size_t)(rg + 0) * 8 + off) = acc0;
        if (rg + 1 < nrows) *(float4*)(base + (size_t)(rg + 1) * 8 + off) = acc1;
        if (rg + 2 < nrows) *(float4*)(base + (size_t)(rg + 2) * 8 + off) = acc2;
        if (rg + 3 < nrows) *(float4*)(base + (size_t)(rg + 3) * 8 + off) = acc3;
    }
}

// ---------------------------------------------------------------------------
// Binning (unchanged from R3, proven correct): bucket = dst >> 7.
// packed edge = src | (dst&127)<<17
// ---------------------------------------------------------------------------
__global__ __launch_bounds__(256) void bin_count_kernel(
    const int* __restrict__ ei, int* __restrict__ bucket_cnt)
{
    __shared__ int hist[NB];
    const int t = threadIdx.x;
    for (int i = t; i < NB; i += 256) hist[i] = 0;
    __syncthreads();
    const int stride = gridDim.x * 256;
    for (int e = blockIdx.x * 256 + t; e < N_EDGES; e += stride)
        atomicAdd(&hist[ei[N_EDGES + e] >> BSHIFT], 1);
    __syncthreads();
    for (int i = t; i < NB; i += 256)
        if (hist[i]) atomicAdd(&bucket_cnt[i], hist[i]);
}

__global__ __launch_bounds__(1024) void bucket_scan_kernel(
    const int* __restrict__ bucket_cnt, int* __restrict__ bucket_base,
    int* __restrict__ bucket_cursor)
{
    __shared__ int s[1024];
    const int t = threadIdx.x;
    s[t] = (t < NB) ? bucket_cnt[t] : 0;
    __syncthreads();
    for (int off = 1; off < 1024; off <<= 1) {
        int v = (t >= off) ? s[t - off] : 0;
        __syncthreads();
        s[t] += v;
        __syncthreads();
    }
    if (t < NB) {
        int excl = (t == 0) ? 0 : s[t - 1];
        bucket_base[t]   = excl;
        bucket_cursor[t] = excl;
        if (t == NB - 1) bucket_base[NB] = s[t];
    }
}

__global__ __launch_bounds__(256) void bin_place_kernel(
    const int* __restrict__ ei, int* __restrict__ bucket_cursor,
    int* __restrict__ packed)
{
    __shared__ int cnt[NB];
    __shared__ int base_off[NB];
    __shared__ int cur[NB];
    const int t = threadIdx.x;
    const int chunk = (N_EDGES + PLACE_BLOCKS - 1) / PLACE_BLOCKS;   // 8000
    const int cs = blockIdx.x * chunk;
    const int ce = min(cs + chunk, N_EDGES);

    for (int i = t; i < NB; i += 256) { cnt[i] = 0; cur[i] = 0; }
    __syncthreads();
    for (int e = cs + t; e < ce; e += 256)
        atomicAdd(&cnt[ei[N_EDGES + e] >> BSHIFT], 1);
    __syncthreads();
    for (int i = t; i < NB; i += 256)
        base_off[i] = cnt[i] ? atomicAdd(&bucket_cursor[i], cnt[i]) : 0;
    __syncthreads();
    for (int e = cs + t; e < ce; e += 256) {
        int s = ei[e];
        int d = ei[N_EDGES + e];
        int b = d >> BSHIFT;
        int pos = base_off[b] + atomicAdd(&cur[b], 1);
        packed[pos] = s | ((d & (BNODES - 1)) << 17);
    }
}

// ---------------------------------------------------------------------------
// scatter_bucket1 v2: 1024 threads, int4 edge batches (MLP 4/slot), sliced
// feature table reads (3.2MB per slice -> per-XCD L2 resident). Two slice
// phases accumulate disjoint LDS channels. Flush fuses +b1/relu, sliced out.
// ---------------------------------------------------------------------------
__global__ __launch_bounds__(1024) void scatter_bucket1_kernel(
    const int* __restrict__ bucket_base, const int* __restrict__ packed,
    const float* __restrict__ h_s0, const float* __restrict__ h_s1,
    const float* __restrict__ b1,
    float* __restrict__ h1_s0, float* __restrict__ h1_s1)
{
    __shared__ float acc[BNODES * ACC_STRIDE];
    const int t = threadIdx.x;
    const int b = blockIdx.x;
    for (int i = t; i < BNODES * ACC_STRIDE; i += 1024) acc[i] = 0.f;
    __syncthreads();

    const int bstart = bucket_base[b];
    const int bend   = bucket_base[b + 1];
    const int a0 = (bstart + 3) & ~3;      // aligned body start
    const int a1 = bend & ~3;              // aligned body end
    const int qid = t >> 3;                // 0..127 edge slots
    const int c8  = t & 7;

    const int nh = min(a0, bend) - bstart;             // head scalars (0..3)
    const int nt = (a1 >= a0) ? (bend - a1) : 0;       // tail scalars (0..3)

    #pragma unroll
    for (int sl = 0; sl < 2; ++sl) {
        const float* hs = sl ? h_s1 : h_s0;
        const int cb = sl * 8 + c8;
        for (int e = a0 + qid * 4; e < a1; e += 128 * 4) {
            int4 p = *(const int4*)(packed + e);
            float v0 = hs[(size_t)(p.x & 0x1FFFF) * 8 + c8];
            float v1 = hs[(size_t)(p.y & 0x1FFFF) * 8 + c8];
            float v2 = hs[(size_t)(p.z & 0x1FFFF) * 8 + c8];
            float v3 = hs[(size_t)(p.w & 0x1FFFF) * 8 + c8];
            atomicAdd(&acc[(p.x >> 17) * ACC_STRIDE + cb], v0);
            atomicAdd(&acc[(p.y >> 17) * ACC_STRIDE + cb], v1);
            atomicAdd(&acc[(p.z >> 17) * ACC_STRIDE + cb], v2);
            atomicAdd(&acc[(p.w >> 17) * ACC_STRIDE + cb], v3);
        }
        if (qid < nh + nt) {
            int e = (qid < nh) ? (bstart + qid) : (a1 + (qid - nh));
            int p = packed[e];
            float v = hs[(size_t)(p & 0x1FFFF) * 8 + c8];
            atomicAdd(&acc[(p >> 17) * ACC_STRIDE + cb], v);
        }
    }
    __syncthreads();

    // flush: 512 threads x float4 = 128 nodes x 16 ch, fused bias+relu
    if (t < 512) {
        int node = t >> 2;
        int cq   = (t & 3) * 4;
        int g    = b * BNODES + node;
        if (g < N_NODES) {
            float4 v;
            v.x = fmaxf(acc[node * ACC_STRIDE + cq + 0] + b1[cq + 0], 0.f);
            v.y = fmaxf(acc[node * ACC_STRIDE + cq + 1] + b1[cq + 1], 0.f);
            v.z = fmaxf(acc[node * ACC_STRIDE + cq + 2] + b1[cq + 2], 0.f);
            v.w = fmaxf(acc[node * ACC_STRIDE + cq + 3] + b1[cq + 3], 0.f);
            float* base = (cq < 8) ? h1_s0 : h1_s1;
            *(float4*)(base + (size_t)g * 8 + (cq & 7)) = v;
        }
    }
}

// ---------------------------------------------------------------------------
// scatter_bucket2 v2: same accumulation over sliced h1; epilogue fuses
// gemm2 (16->40) + bias + log_softmax (threads 0..127, one node each).
// ---------------------------------------------------------------------------
__global__ __launch_bounds__(1024) void scatter_bucket2_kernel(
    const int* __restrict__ bucket_base, const int* __restrict__ packed,
    const float* __restrict__ h1_s0, const float* __restrict__ h1_s1,
    const float* __restrict__ W2, const float* __restrict__ b2,
    float* __restrict__ out)
{
    __shared__ float acc[BNODES * ACC_STRIDE];
    __shared__ float4 w2s[160];     // 16x40 floats
    __shared__ float4 b2s[10];      // 40 floats
    const int t = threadIdx.x;
    const int b = blockIdx.x;
    for (int i = t; i < BNODES * ACC_STRIDE; i += 1024) acc[i] = 0.f;
    if (t < 160) w2s[t] = ((const float4*)W2)[t];
    else if (t < 170) b2s[t - 160] = ((const float4*)b2)[t - 160];
    __syncthreads();

    const int bstart = bucket_base[b];
    const int bend   = bucket_base[b + 1];
    const int a0 = (bstart + 3) & ~3;
    const int a1 = bend & ~3;
    const int qid = t >> 3;
    const int c8  = t & 7;

    const int nh = min(a0, bend) - bstart;
    const int nt = (a1 >= a0) ? (bend - a1) : 0;

    #pragma unroll
    for (int sl = 0; sl < 2; ++sl) {
        const float* hs = sl ? h1_s1 : h1_s0;
        const int cb = sl * 8 + c8;
        for (int e = a0 + qid * 4; e < a1; e += 128 * 4) {
            int4 p = *(const int4*)(packed + e);
            float v0 = hs[(size_t)(p.x & 0x1FFFF) * 8 + c8];
            float v1 = hs[(size_t)(p.y & 0x1FFFF) * 8 + c8];
            float v2 = hs[(size_t)(p.z & 0x1FFFF) * 8 + c8];
            float v3 = hs[(size_t)(p.w & 0x1FFFF) * 8 + c8];
            atomicAdd(&acc[(p.x >> 17) * ACC_STRIDE + cb], v0);
            atomicAdd(&acc[(p.y >> 17) * ACC_STRIDE + cb], v1);
            atomicAdd(&acc[(p.z >> 17) * ACC_STRIDE + cb], v2);
            atomicAdd(&acc[(p.w >> 17) * ACC_STRIDE + cb], v3);
        }
        if (qid < nh + nt) {
            int e = (qid < nh) ? (bstart + qid) : (a1 + (qid - nh));
            int p = packed[e];
            float v = hs[(size_t)(p & 0x1FFFF) * 8 + c8];
            atomicAdd(&acc[(p >> 17) * ACC_STRIDE + cb], v);
        }
    }
    __syncthreads();

    if (t < BNODES) {
        int g = b * BNODES + t;
        if (g < N_NODES) {
            float a[16];
            #pragma unroll
            for (int k = 0; k < 16; ++k) a[k] = acc[t * ACC_STRIDE + k];

            float4 z[10];
            #pragma unroll
            for (int c4 = 0; c4 < 10; ++c4) z[c4] = b2s[c4];
            #pragma unroll
            for (int k = 0; k < 16; ++k) {
                const float av = a[k];
                #pragma unroll
                for (int c4 = 0; c4 < 10; ++c4) {
                    float4 w = w2s[k * 10 + c4];
                    z[c4].x += av * w.x;
                    z[c4].y += av * w.y;
                    z[c4].z += av * w.z;
                    z[c4].w += av * w.w;
                }
            }
            float m = z[0].x;
            #pragma unroll
            for (int c4 = 0; c4 < 10; ++c4) {
                m = fmaxf(m, z[c4].x); m = fmaxf(m, z[c4].y);
                m = fmaxf(m, z[c4].z); m = fmaxf(m, z[c4].w);
            }
            float s = 0.f;
            #pragma unroll
            for (int c4 = 0; c4 < 10; ++c4) {
                s += __expf(z[c4].x - m); s += __expf(z[c4].y - m);
                s += __expf(z[c4].z - m); s += __expf(z[c4].w - m);
            }
            const float lse = m + __logf(s);
            float4* op = (float4*)(out + (size_t)g * 40);
            #pragma unroll
            for (int c4 = 0; c4 < 10; ++c4) {
                float4 o;
                o.x = z[c4].x - lse; o.y = z[c4].y - lse;
                o.z = z[c4].z - lse; o.w = z[c4].w - lse;
                op[c4] = o;
            }
        }
    }
}

// ---------------------------------------------------------------------------
extern "C" void kernel_launch(void* const* d_in, const int* in_sizes, int n_in,
                              void* d_out, int out_size, void* d_ws, size_t ws_size,
                              hipStream_t stream)
{
    const float* x  = (const float*)d_in[0];
    const int*   ei = (const int*)d_in[1];
    const float* W1 = (const float*)d_in[2];
    const float* b1 = (const float*)d_in[3];
    const float* W2 = (const float*)d_in[4];
    const float* b2 = (const float*)d_in[5];
    float* out = (float*)d_out;

    // ws: h_s0/h_s1/h1_s0/h1_s1 (each N*8 f32 = 3.2MB), packed (E int),
    //     bcnt (NB), bbase (NB+1), bcur (NB)
    float* h_s0  = (float*)d_ws;
    float* h_s1  = h_s0  + (size_t)N_NODES * 8;
    float* h1_s0 = h_s1  + (size_t)N_NODES * 8;
    float* h1_s1 = h1_s0 + (size_t)N_NODES * 8;
    int* packed  = (int*)(h1_s1 + (size_t)N_NODES * 8);
    int* bcnt    = packed + N_EDGES;
    int* bbase   = bcnt + NB;
    int* bcur    = bbase + (NB + 1);

    const int node_blocks = (N_NODES + 255) / 256;   // 391

    hipMemsetAsync(bcnt, 0, NB * sizeof(int), stream);
    bin_count_kernel  <<<256, 256, 0, stream>>>(ei, bcnt);
    bucket_scan_kernel<<<1, 1024, 0, stream>>>(bcnt, bbase, bcur);
    bin_place_kernel  <<<PLACE_BLOCKS, 256, 0, stream>>>(ei, bcur, packed);

    gemm1_kernel<<<node_blocks, 256, 0, stream>>>(x, W1, h_s0, h_s1, N_NODES);

    scatter_bucket1_kernel<<<NB, 1024, 0, stream>>>(bbase, packed, h_s0, h_s1,
                                                    b1, h1_s0, h1_s1);
    scatter_bucket2_kernel<<<NB, 1024, 0, stream>>>(bbase, packed, h1_s0, h1_s1,
                                                    W2, b2, out);
}

// Round 5
// 604.553 us; speedup vs baseline: 1.8859x; 1.8840x over previous
//
#include <hip/hip_runtime.h>
#include <math.h>

#define N_NODES 100000
#define N_EDGES 3200000
#define BSHIFT 7
#define BNODES 128                         // nodes per bucket
#define NB 782                             // ceil(N_NODES/128)
#define PLACE_BLOCKS 400

// ---------------------------------------------------------------------------
// gemm1: h[N,16] = x[N,512] @ W1[512,16]  (R1 version, interleaved output)
// ---------------------------------------------------------------------------
__global__ __launch_bounds__(256) void gemm1_kernel(
    const float* __restrict__ x, const float* __restrict__ W1,
    float* __restrict__ h, int nrows)
{
    __shared__ float xs[32 * 260];
    const int t = threadIdx.x;
    const int rbase = blockIdx.x * 256;
    const int rq = t >> 2;
    const int cg = t & 3;

    float4 acc0 = make_float4(0.f, 0.f, 0.f, 0.f);
    float4 acc1 = acc0, acc2 = acc0, acc3 = acc0;

    const int kl4  = (t & 7) * 4;
    const int rstg = t >> 3;
    const float4* w4 = (const float4*)W1;

    for (int kc = 0; kc < 512; kc += 32) {
        #pragma unroll
        for (int i = 0; i < 8; ++i) {
            int row = rstg + i * 32;
            int rg  = rbase + row;
            float4 v = make_float4(0.f, 0.f, 0.f, 0.f);
            if (rg < nrows)
                v = *(const float4*)(x + (size_t)rg * 512 + kc + kl4);
            xs[(kl4 + 0) * 260 + row] = v.x;
            xs[(kl4 + 1) * 260 + row] = v.y;
            xs[(kl4 + 2) * 260 + row] = v.z;
            xs[(kl4 + 3) * 260 + row] = v.w;
        }
        __syncthreads();

        #pragma unroll
        for (int k4 = 0; k4 < 8; ++k4) {
            const int k0 = k4 * 4;
            float4 xv0 = *(const float4*)(xs + (k0 + 0) * 260 + rq * 4);
            float4 xv1 = *(const float4*)(xs + (k0 + 1) * 260 + rq * 4);
            float4 xv2 = *(const float4*)(xs + (k0 + 2) * 260 + rq * 4);
            float4 xv3 = *(const float4*)(xs + (k0 + 3) * 260 + rq * 4);
            float4 wv0 = w4[(kc + k0 + 0) * 4 + cg];
            float4 wv1 = w4[(kc + k0 + 1) * 4 + cg];
            float4 wv2 = w4[(kc + k0 + 2) * 4 + cg];
            float4 wv3 = w4[(kc + k0 + 3) * 4 + cg];

            #define GCN_UPD(xv, wv)                                           \
                acc0.x += (xv).x * (wv).x; acc0.y += (xv).x * (wv).y;         \
                acc0.z += (xv).x * (wv).z; acc0.w += (xv).x * (wv).w;         \
                acc1.x += (xv).y * (wv).x; acc1.y += (xv).y * (wv).y;         \
                acc1.z += (xv).y * (wv).z; acc1.w += (xv).y * (wv).w;         \
                acc2.x += (xv).z * (wv).x; acc2.y += (xv).z * (wv).y;         \
                acc2.z += (xv).z * (wv).z; acc2.w += (xv).z * (wv).w;         \
                acc3.x += (xv).w * (wv).x; acc3.y += (xv).w * (wv).y;         \
                acc3.z += (xv).w * (wv).z; acc3.w += (xv).w * (wv).w;
            GCN_UPD(xv0, wv0)
            GCN_UPD(xv1, wv1)
            GCN_UPD(xv2, wv2)
            GCN_UPD(xv3, wv3)
            #undef GCN_UPD
        }
        __syncthreads();
    }
    {
        int rg = rbase + rq * 4;
        if (rg + 0 < nrows) *(float4*)(h + (size_t)(rg + 0) * 16 + cg * 4) = acc0;
        if (rg + 1 < nrows) *(float4*)(h + (size_t)(rg + 1) * 16 + cg * 4) = acc1;
        if (rg + 2 < nrows) *(float4*)(h + (size_t)(rg + 2) * 16 + cg * 4) = acc2;
        if (rg + 3 < nrows) *(float4*)(h + (size_t)(rg + 3) * 16 + cg * 4) = acc3;
    }
}

// ---------------------------------------------------------------------------
// Binning (unchanged, proven): bucket = dst>>7, packed = src | (dst&127)<<17
// ---------------------------------------------------------------------------
__global__ __launch_bounds__(256) void bin_count_kernel(
    const int* __restrict__ ei, int* __restrict__ bucket_cnt)
{
    __shared__ int hist[NB];
    const int t = threadIdx.x;
    for (int i = t; i < NB; i += 256) hist[i] = 0;
    __syncthreads();
    const int stride = gridDim.x * 256;
    for (int e = blockIdx.x * 256 + t; e < N_EDGES; e += stride)
        atomicAdd(&hist[ei[N_EDGES + e] >> BSHIFT], 1);
    __syncthreads();
    for (int i = t; i < NB; i += 256)
        if (hist[i]) atomicAdd(&bucket_cnt[i], hist[i]);
}

__global__ __launch_bounds__(1024) void bucket_scan_kernel(
    const int* __restrict__ bucket_cnt, int* __restrict__ bucket_base,
    int* __restrict__ bucket_cursor)
{
    __shared__ int s[1024];
    const int t = threadIdx.x;
    s[t] = (t < NB) ? bucket_cnt[t] : 0;
    __syncthreads();
    for (int off = 1; off < 1024; off <<= 1) {
        int v = (t >= off) ? s[t - off] : 0;
        __syncthreads();
        s[t] += v;
        __syncthreads();
    }
    if (t < NB) {
        int excl = (t == 0) ? 0 : s[t - 1];
        bucket_base[t]   = excl;
        bucket_cursor[t] = excl;
        if (t == NB - 1) bucket_base[NB] = s[t];
    }
}

__global__ __launch_bounds__(256) void bin_place_kernel(
    const int* __restrict__ ei, int* __restrict__ bucket_cursor,
    int* __restrict__ packed)
{
    __shared__ int cnt[NB];
    __shared__ int base_off[NB];
    __shared__ int cur[NB];
    const int t = threadIdx.x;
    const int chunk = (N_EDGES + PLACE_BLOCKS - 1) / PLACE_BLOCKS;   // 8000
    const int cs = blockIdx.x * chunk;
    const int ce = min(cs + chunk, N_EDGES);

    for (int i = t; i < NB; i += 256) { cnt[i] = 0; cur[i] = 0; }
    __syncthreads();
    for (int e = cs + t; e < ce; e += 256)
        atomicAdd(&cnt[ei[N_EDGES + e] >> BSHIFT], 1);
    __syncthreads();
    for (int i = t; i < NB; i += 256)
        base_off[i] = cnt[i] ? atomicAdd(&bucket_cursor[i], cnt[i]) : 0;
    __syncthreads();
    for (int e = cs + t; e < ce; e += 256) {
        int s = ei[e];
        int d = ei[N_EDGES + e];
        int b = d >> BSHIFT;
        int pos = base_off[b] + atomicAdd(&cur[b], 1);
        packed[pos] = s | ((d & (BNODES - 1)) << 17);
    }
}

// ---------------------------------------------------------------------------
// csr_sort: one block per bucket. Counting sort by dst_local -> full
// dst-sorted csr_src + row_ptr. Each block writes ONLY its own contiguous
// ~16KB window -> lines stay dirty in its L2 until written back once.
// ---------------------------------------------------------------------------
__global__ __launch_bounds__(256) void csr_sort_kernel(
    const int* __restrict__ bucket_base, const int* __restrict__ packed,
    int* __restrict__ csr_src, int* __restrict__ row_ptr)
{
    __shared__ int hist[BNODES];
    __shared__ int excl[BNODES];
    __shared__ int cur[BNODES];
    __shared__ int scan[BNODES];
    const int t = threadIdx.x;
    const int b = blockIdx.x;
    if (t < BNODES) { hist[t] = 0; cur[t] = 0; }
    __syncthreads();

    const int bs = bucket_base[b];
    const int be = bucket_base[b + 1];
    for (int e = bs + t; e < be; e += 256)
        atomicAdd(&hist[packed[e] >> 17], 1);
    __syncthreads();

    if (t < BNODES) scan[t] = hist[t];
    __syncthreads();
    for (int off = 1; off < BNODES; off <<= 1) {
        int v = (t < BNODES && t >= off) ? scan[t - off] : 0;
        __syncthreads();
        if (t < BNODES) scan[t] += v;
        __syncthreads();
    }
    if (t < BNODES) {
        int ex = (t == 0) ? 0 : scan[t - 1];
        excl[t] = ex;
        int g = b * BNODES + t;
        if (g < N_NODES) row_ptr[g] = bs + ex;
    }
    if (b == NB - 1 && t == 0) row_ptr[N_NODES] = N_EDGES;
    __syncthreads();

    for (int e = bs + t; e < be; e += 256) {
        int p  = packed[e];
        int dl = p >> 17;
        int pos = bs + excl[dl] + atomicAdd(&cur[dl], 1);
        csr_src[pos] = p & 0x1FFFF;
    }
}

// ---------------------------------------------------------------------------
// gather1: wave per node, 64 lanes = 4 edge slots x 16 channels.
// Main loop 16 edges/iter -> 8 independent loads in flight per wave.
// Epilogue fuses +b1 / relu.
// ---------------------------------------------------------------------------
__global__ __launch_bounds__(256) void gather1_kernel(
    const int* __restrict__ row_ptr, const int* __restrict__ csr_src,
    const float* __restrict__ h, const float* __restrict__ b1,
    float* __restrict__ h1)
{
    const int node = (blockIdx.x * 256 + threadIdx.x) >> 6;
    if (node >= N_NODES) return;
    const int lane = threadIdx.x & 63;
    const int c = lane & 15, slot = lane >> 4;
    const int start = row_ptr[node], end = row_ptr[node + 1];

    float acc = 0.f;
    int e = start;
    for (; e + 16 <= end; e += 16) {
        int s0 = csr_src[e + slot * 4 + 0];
        int s1 = csr_src[e + slot * 4 + 1];
        int s2 = csr_src[e + slot * 4 + 2];
        int s3 = csr_src[e + slot * 4 + 3];
        float v0 = h[s0 * 16 + c];
        float v1 = h[s1 * 16 + c];
        float v2 = h[s2 * 16 + c];
        float v3 = h[s3 * 16 + c];
        acc += (v0 + v1) + (v2 + v3);
    }
    for (; e + 4 <= end; e += 4)
        acc += h[csr_src[e + slot] * 16 + c];
    if (e + slot < end)
        acc += h[csr_src[e + slot] * 16 + c];

    acc += __shfl_xor(acc, 16);
    acc += __shfl_xor(acc, 32);
    if (lane < 16)
        h1[(size_t)node * 16 + c] = fmaxf(acc + b1[c], 0.f);
}

// ---------------------------------------------------------------------------
// gather2 + gemm2 + bias + log_softmax, fully in-wave (shuffle-based).
// lane j<40 accumulates z_j = b2[j] + sum_k agg[k]*W2[k][j]; softmax via
// butterfly shuffles; writes out[node*40 + j].
// ---------------------------------------------------------------------------
__global__ __launch_bounds__(256) void gather2_kernel(
    const int* __restrict__ row_ptr, const int* __restrict__ csr_src,
    const float* __restrict__ h1, const float* __restrict__ W2,
    const float* __restrict__ b2, float* __restrict__ out)
{
    const int node = (blockIdx.x * 256 + threadIdx.x) >> 6;
    if (node >= N_NODES) return;
    const int lane = threadIdx.x & 63;
    const int c = lane & 15, slot = lane >> 4;

    // stage W2 column `lane` + b2[lane] in registers (coalesced, L1-hot)
    float w2c[16];
    float b2v = 0.f;
    if (lane < 40) {
        b2v = b2[lane];
        #pragma unroll
        for (int k = 0; k < 16; ++k) w2c[k] = W2[k * 40 + lane];
    } else {
        #pragma unroll
        for (int k = 0; k < 16; ++k) w2c[k] = 0.f;
    }

    const int start = row_ptr[node], end = row_ptr[node + 1];
    float acc = 0.f;
    int e = start;
    for (; e + 16 <= end; e += 16) {
        int s0 = csr_src[e + slot * 4 + 0];
        int s1 = csr_src[e + slot * 4 + 1];
        int s2 = csr_src[e + slot * 4 + 2];
        int s3 = csr_src[e + slot * 4 + 3];
        float v0 = h1[s0 * 16 + c];
        float v1 = h1[s1 * 16 + c];
        float v2 = h1[s2 * 16 + c];
        float v3 = h1[s3 * 16 + c];
        acc += (v0 + v1) + (v2 + v3);
    }
    for (; e + 4 <= end; e += 4)
        acc += h1[csr_src[e + slot] * 16 + c];
    if (e + slot < end)
        acc += h1[csr_src[e + slot] * 16 + c];

    acc += __shfl_xor(acc, 16);
    acc += __shfl_xor(acc, 32);
    // now lane k (any slot) holds channel (k&15) aggregate

    float z = b2v;
    #pragma unroll
    for (int k = 0; k < 16; ++k)
        z += __shfl(acc, k) * w2c[k];

    float zm = (lane < 40) ? z : -1e30f;
    #pragma unroll
    for (int off = 1; off < 64; off <<= 1)
        zm = fmaxf(zm, __shfl_xor(zm, off));
    float ex = (lane < 40) ? __expf(z - zm) : 0.f;
    float sum = ex;
    #pragma unroll
    for (int off = 1; off < 64; off <<= 1)
        sum += __shfl_xor(sum, off);
    const float lse = zm + __logf(sum);

    if (lane < 40)
        out[(size_t)node * 40 + lane] = z - lse;
}

// ---------------------------------------------------------------------------
extern "C" void kernel_launch(void* const* d_in, const int* in_sizes, int n_in,
                              void* d_out, int out_size, void* d_ws, size_t ws_size,
                              hipStream_t stream)
{
    const float* x  = (const float*)d_in[0];
    const int*   ei = (const int*)d_in[1];
    const float* W1 = (const float*)d_in[2];
    const float* b1 = (const float*)d_in[3];
    const float* W2 = (const float*)d_in[4];
    const float* b2 = (const float*)d_in[5];
    float* out = (float*)d_out;

    // ws (~32.4 MB): h (6.4MB) | csr (12.8MB) | packed (12.8MB, h1 overlays
    // its first 6.4MB after csr_sort) | rowp | bcnt | bbase | bcur
    float* h      = (float*)d_ws;
    int*   csr    = (int*)(h + (size_t)N_NODES * 16);
    int*   packed = csr + N_EDGES;
    float* h1     = (float*)packed;            // packed dead after csr_sort
    int*   rowp   = packed + N_EDGES;
    int*   bcnt   = rowp + (N_NODES + 1);
    int*   bbase  = bcnt + NB;
    int*   bcur   = bbase + (NB + 1);

    const int node_blocks   = (N_NODES + 255) / 256;        // 391
    const int gather_blocks = (N_NODES + 3) / 4;            // 25000

    hipMemsetAsync(bcnt, 0, NB * sizeof(int), stream);
    bin_count_kernel  <<<256, 256, 0, stream>>>(ei, bcnt);
    bucket_scan_kernel<<<1, 1024, 0, stream>>>(bcnt, bbase, bcur);
    bin_place_kernel  <<<PLACE_BLOCKS, 256, 0, stream>>>(ei, bcur, packed);
    csr_sort_kernel   <<<NB, 256, 0, stream>>>(bbase, packed, csr, rowp);

    gemm1_kernel<<<node_blocks, 256, 0, stream>>>(x, W1, h, N_NODES);

    gather1_kernel<<<gather_blocks, 256, 0, stream>>>(rowp, csr, h, b1, h1);
    gather2_kernel<<<gather_blocks, 256, 0, stream>>>(rowp, csr, h1, W2, b2, out);
}